// Round 2
// baseline (391.153 us; speedup 1.0000x reference)
//
#include <hip/hip_runtime.h>
#include <stdint.h>

#define IN_DIM  4096
#define OUT_DIM 4096
#define BATCH   4096
#define NACT    32

// ---------------------------------------------------------------------------
// Kernel 1: compress mask+weight -> idx_tab[OUT_DIM][32], w_tab[OUT_DIM][32]
// One block per output row. Deterministic (LDS prefix scan, no atomics).
// ---------------------------------------------------------------------------
__global__ __launch_bounds__(256)
void compress_kernel(const float* __restrict__ weight,
                     const int*   __restrict__ mask,
                     int*         __restrict__ idx_tab,
                     float*       __restrict__ w_tab) {
    const int o = blockIdx.x;
    const int t = threadIdx.x;            // 256 threads
    const int PER = IN_DIM / 256;         // 16 mask entries per thread
    __shared__ int scan[256];

    const int* mrow = mask + (size_t)o * IN_DIM;
    const int  base = t * PER;

    int c = 0;
    #pragma unroll
    for (int j = 0; j < PER; ++j) c += (mrow[base + j] != 0);

    scan[t] = c;
    __syncthreads();
    // Hillis-Steele inclusive scan over 256 entries
    for (int off = 1; off < 256; off <<= 1) {
        int add = (t >= off) ? scan[t - off] : 0;
        __syncthreads();
        scan[t] += add;
        __syncthreads();
    }
    int pos = scan[t] - c;                // exclusive prefix
    for (int j = 0; j < PER; ++j) {
        if (mrow[base + j] != 0) {
            int idx = base + j;
            idx_tab[o * NACT + pos] = idx;
            w_tab [o * NACT + pos] = weight[(size_t)o * IN_DIM + idx];
            ++pos;
        }
    }
}

// ---------------------------------------------------------------------------
// Kernel 2: transpose x [BATCH][IN_DIM] -> xT [IN_DIM][BATCH] (f32)
// 64x64 tiles via LDS (pad 65 -> conflict-light).
// ---------------------------------------------------------------------------
__global__ __launch_bounds__(256)
void transpose_kernel(const float* __restrict__ x, float* __restrict__ xT) {
    __shared__ float tile[64][65];
    const int t  = threadIdx.x;
    const int bi = blockIdx.x;            // batch tile
    const int bj = blockIdx.y;            // in-dim tile
    const int c  = t & 63;                // lane within row
    const int r0 = t >> 6;                // 4 rows per pass

    #pragma unroll
    for (int j = 0; j < 16; ++j) {
        int r = r0 + j * 4;               // batch-local
        tile[r][c] = x[(size_t)(bi * 64 + r) * IN_DIM + bj * 64 + c];
    }
    __syncthreads();
    #pragma unroll
    for (int j = 0; j < 16; ++j) {
        int r = r0 + j * 4;               // in-dim local
        xT[(size_t)(bj * 64 + r) * BATCH + bi * 64 + c] = tile[c][r];
    }
}

// ---------------------------------------------------------------------------
// Kernel 3: main sparse matmul using xT.
// Block: 256 threads, thread t owns batches b0+4t..+3 (one float4 of xT row).
// Each block: 16 outputs x 1024 batches. Grid = 256 o-tiles * 4 b-slabs.
// XCD swizzle: o-tile minor within each XCD chunk -> same b-slab resident.
// ---------------------------------------------------------------------------
__global__ __launch_bounds__(256)
void spmm_kernel(const float* __restrict__ xT,
                 const int*   __restrict__ idx_tab,
                 const float* __restrict__ w_tab,
                 const float* __restrict__ bias,
                 float*       __restrict__ out) {
    const int t   = threadIdx.x;
    const int nwg = gridDim.x;            // 1024 (divisible by 8)
    const int bid = blockIdx.x;
    // bijective XCD swizzle: XCD x gets contiguous virtual chunk
    const int v  = (bid & 7) * (nwg >> 3) + (bid >> 3);
    const int ob = v & 255;               // 256 o-tiles (minor)
    const int bb = v >> 8;                // 4 batch slabs
    const int o0  = ob * 16;
    const int b04 = bb * 256;             // batch-slab base / 4

    const float4* xt4 = (const float4*)xT;

    #pragma unroll 1
    for (int o = 0; o < 16; ++o) {
        const int*   ip = idx_tab + (size_t)(o0 + o) * NACT;
        const float* wp = w_tab   + (size_t)(o0 + o) * NACT;
        float4 a = {0.f, 0.f, 0.f, 0.f};
        #pragma unroll
        for (int k = 0; k < NACT; ++k) {
            int   i = ip[k];              // uniform -> s_load
            float w = wp[k];              // uniform -> s_load
            float4 xv = xt4[(size_t)i * (BATCH / 4) + b04 + t];
            a.x = fmaf(w, xv.x, a.x);
            a.y = fmaf(w, xv.y, a.y);
            a.z = fmaf(w, xv.z, a.z);
            a.w = fmaf(w, xv.w, a.w);
        }
        const float bo = bias[o0 + o];
        const size_t b0 = (size_t)bb * 1024 + (size_t)t * 4;
        float* op = out + b0 * OUT_DIM + (o0 + o);
        op[0 * OUT_DIM] = a.x - bo;
        op[1 * OUT_DIM] = a.y - bo;
        op[2 * OUT_DIM] = a.z - bo;
        op[3 * OUT_DIM] = a.w - bo;
    }
}

// ---------------------------------------------------------------------------
// Fallback A (ws >= table only): same as spmm but gathers from x directly
// (uncoalesced, correct).
// ---------------------------------------------------------------------------
__global__ __launch_bounds__(256)
void spmm_noT_kernel(const float* __restrict__ x,
                     const int*   __restrict__ idx_tab,
                     const float* __restrict__ w_tab,
                     const float* __restrict__ bias,
                     float*       __restrict__ out) {
    const int t   = threadIdx.x;
    const int bid = blockIdx.x;
    const int ob  = bid & 255;
    const int bb  = bid >> 8;
    const int o0  = ob * 16;

    #pragma unroll 1
    for (int o = 0; o < 16; ++o) {
        const int*   ip = idx_tab + (size_t)(o0 + o) * NACT;
        const float* wp = w_tab   + (size_t)(o0 + o) * NACT;
        float4 a = {0.f, 0.f, 0.f, 0.f};
        const size_t b0 = (size_t)bb * 1024 + (size_t)t * 4;
        for (int k = 0; k < NACT; ++k) {
            int   i = ip[k];
            float w = wp[k];
            a.x = fmaf(w, x[(b0 + 0) * IN_DIM + i], a.x);
            a.y = fmaf(w, x[(b0 + 1) * IN_DIM + i], a.y);
            a.z = fmaf(w, x[(b0 + 2) * IN_DIM + i], a.z);
            a.w = fmaf(w, x[(b0 + 3) * IN_DIM + i], a.w);
        }
        const float bo = bias[o0 + o];
        float* op = out + b0 * OUT_DIM + (o0 + o);
        op[0 * OUT_DIM] = a.x - bo;
        op[1 * OUT_DIM] = a.y - bo;
        op[2 * OUT_DIM] = a.z - bo;
        op[3 * OUT_DIM] = a.w - bo;
    }
}

// ---------------------------------------------------------------------------
// Fallback B (tiny ws): block per output row; inline compress into LDS,
// then stride over batches. Slow but correct and ws-free.
// ---------------------------------------------------------------------------
__global__ __launch_bounds__(256)
void naive_kernel(const float* __restrict__ x,
                  const float* __restrict__ weight,
                  const float* __restrict__ bias,
                  const int*   __restrict__ mask,
                  float*       __restrict__ out) {
    const int o = blockIdx.x;
    const int t = threadIdx.x;
    const int PER = IN_DIM / 256;
    __shared__ int   scan[256];
    __shared__ int   sidx[NACT];
    __shared__ float sw[NACT];

    const int* mrow = mask + (size_t)o * IN_DIM;
    const int  base = t * PER;
    int c = 0;
    #pragma unroll
    for (int j = 0; j < PER; ++j) c += (mrow[base + j] != 0);
    scan[t] = c;
    __syncthreads();
    for (int off = 1; off < 256; off <<= 1) {
        int add = (t >= off) ? scan[t - off] : 0;
        __syncthreads();
        scan[t] += add;
        __syncthreads();
    }
    int pos = scan[t] - c;
    for (int j = 0; j < PER; ++j) {
        if (mrow[base + j] != 0) {
            sidx[pos] = base + j;
            sw[pos]   = weight[(size_t)o * IN_DIM + base + j];
            ++pos;
        }
    }
    __syncthreads();
    const float bo = bias[o];
    for (int b = t; b < BATCH; b += 256) {
        float a = 0.f;
        #pragma unroll
        for (int k = 0; k < NACT; ++k)
            a = fmaf(sw[k], x[(size_t)b * IN_DIM + sidx[k]], a);
        out[(size_t)b * OUT_DIM + o] = a - bo;
    }
}

// ---------------------------------------------------------------------------
extern "C" void kernel_launch(void* const* d_in, const int* in_sizes, int n_in,
                              void* d_out, int out_size, void* d_ws, size_t ws_size,
                              hipStream_t stream) {
    const float* x      = (const float*)d_in[0];
    const float* weight = (const float*)d_in[1];
    const float* bias   = (const float*)d_in[2];
    const int*   mask   = (const int*)  d_in[3];
    float* out = (float*)d_out;

    const size_t TAB_BYTES  = (size_t)OUT_DIM * NACT * (sizeof(int) + sizeof(float)); // 1 MB
    const size_t XT_BYTES   = (size_t)IN_DIM * BATCH * sizeof(float);                 // 64 MB
    const size_t NEED_FULL  = TAB_BYTES + XT_BYTES;

    if (ws_size >= NEED_FULL) {
        int*   idx_tab = (int*)d_ws;
        float* w_tab   = (float*)((char*)d_ws + (size_t)OUT_DIM * NACT * sizeof(int));
        float* xT      = (float*)((char*)d_ws + TAB_BYTES);

        compress_kernel<<<OUT_DIM, 256, 0, stream>>>(weight, mask, idx_tab, w_tab);
        dim3 tgrid(BATCH / 64, IN_DIM / 64);
        transpose_kernel<<<tgrid, 256, 0, stream>>>(x, xT);
        spmm_kernel<<<1024, 256, 0, stream>>>(xT, idx_tab, w_tab, bias, out);
    } else if (ws_size >= TAB_BYTES) {
        int*   idx_tab = (int*)d_ws;
        float* w_tab   = (float*)((char*)d_ws + (size_t)OUT_DIM * NACT * sizeof(int));
        compress_kernel<<<OUT_DIM, 256, 0, stream>>>(weight, mask, idx_tab, w_tab);
        spmm_noT_kernel<<<1024, 256, 0, stream>>>(x, idx_tab, w_tab, bias, out);
    } else {
        naive_kernel<<<OUT_DIM, 256, 0, stream>>>(x, weight, bias, mask, out);
    }
}

// Round 3
// 164.244 us; speedup vs baseline: 2.3815x; 2.3815x over previous
//
#include <hip/hip_runtime.h>
#include <stdint.h>

#define IN_DIM  4096
#define OUT_DIM 4096
#define BATCH   4096
#define NACT    32

// ---------------------------------------------------------------------------
// Kernel 1: compress mask+weight -> idx_tab[OUT_DIM][32], w_tab[OUT_DIM][32]
// One block per output row. Deterministic (LDS prefix scan, no atomics).
// ---------------------------------------------------------------------------
__global__ __launch_bounds__(256)
void compress_kernel(const float* __restrict__ weight,
                     const int*   __restrict__ mask,
                     int*         __restrict__ idx_tab,
                     float*       __restrict__ w_tab) {
    const int o = blockIdx.x;
    const int t = threadIdx.x;            // 256 threads
    __shared__ int scan[256];

    const int* mrow = mask + (size_t)o * IN_DIM;
    const int  base = t * 16;             // 16 mask entries per thread

    // vectorized mask read: 4x int4
    int m[16];
    const int4* m4 = (const int4*)(mrow + base);
    #pragma unroll
    for (int j = 0; j < 4; ++j) {
        int4 v = m4[j];
        m[j*4+0] = v.x; m[j*4+1] = v.y; m[j*4+2] = v.z; m[j*4+3] = v.w;
    }
    int c = 0;
    #pragma unroll
    for (int j = 0; j < 16; ++j) c += (m[j] != 0);

    scan[t] = c;
    __syncthreads();
    // Hillis-Steele inclusive scan over 256 entries
    for (int off = 1; off < 256; off <<= 1) {
        int add = (t >= off) ? scan[t - off] : 0;
        __syncthreads();
        scan[t] += add;
        __syncthreads();
    }
    int pos = scan[t] - c;                // exclusive prefix
    for (int j = 0; j < 16; ++j) {
        if (m[j] != 0) {
            int idx = base + j;
            idx_tab[o * NACT + pos] = idx;
            w_tab [o * NACT + pos] = weight[(size_t)o * IN_DIM + idx];
            ++pos;
        }
    }
}

// ---------------------------------------------------------------------------
// Kernel 2: transpose x [BATCH][IN_DIM] -> xT [IN_DIM][BATCH] (f32)
// 64x64 tile, float4 global on BOTH sides, LDS pad-65 (2-way only = free).
// ---------------------------------------------------------------------------
__global__ __launch_bounds__(256)
void transpose_kernel(const float* __restrict__ x, float* __restrict__ xT) {
    __shared__ float tile[64][65];
    const int t  = threadIdx.x;
    const int bi = blockIdx.x;            // batch tile (rows of x)
    const int bj = blockIdx.y;            // in-dim tile (cols of x)

    {   // load: row r = (t>>4)+16p, float4 col c = t&15
        const int c = (t & 15) * 4;
        const int r0 = t >> 4;
        #pragma unroll
        for (int p = 0; p < 4; ++p) {
            int r = r0 + p * 16;
            float4 v = *(const float4*)(x + (size_t)(bi*64 + r) * IN_DIM + bj*64 + c);
            tile[r][c+0] = v.x; tile[r][c+1] = v.y;
            tile[r][c+2] = v.z; tile[r][c+3] = v.w;
        }
    }
    __syncthreads();
    {   // store: output row j (= input col), float4 over batch b4 = t&15
        const int b4 = (t & 15) * 4;
        const int j0 = t >> 4;
        #pragma unroll
        for (int p = 0; p < 4; ++p) {
            int j = j0 + p * 16;
            float4 v;
            v.x = tile[b4+0][j]; v.y = tile[b4+1][j];
            v.z = tile[b4+2][j]; v.w = tile[b4+3][j];
            *(float4*)(xT + (size_t)(bj*64 + j) * BATCH + bi*64 + b4) = v;
        }
    }
}

// ---------------------------------------------------------------------------
// Kernel 3: main sparse matmul using xT.
// Thread = 1 batch x 16 consecutive outputs (acc in 16 VGPRs).
// Block = 256 threads = one 256-batch slab x one 16-output tile.
// Slab xT footprint = 4096 rows x 256 b x 4B = 4 MB = one XCD L2.
// Grid = 16 slabs * 256 o-tiles = 4096 blocks. Swizzle: XCD x sweeps
// o-tiles of slabs 2x,2x+1 -> gathered rows stay L2-resident.
// Store: 64 B contiguous per thread = fully-dirty line (no write amp).
// ---------------------------------------------------------------------------
__global__ __launch_bounds__(256)
void spmm_kernel(const float* __restrict__ xT,
                 const int*   __restrict__ idx_tab,
                 const float* __restrict__ w_tab,
                 const float* __restrict__ bias,
                 float*       __restrict__ out) {
    const int t   = threadIdx.x;
    const int bid = blockIdx.x;           // 4096 blocks
    const int v    = (bid & 7) * 512 + (bid >> 3);   // bijective XCD swizzle
    const int slab = v >> 8;              // 0..15 (slab-major per XCD)
    const int ot   = v & 255;             // o-tile minor
    const int o0   = ot * 16;
    const int b    = slab * 256 + t;      // this thread's batch

    const float* xb = xT + b;             // row i lives at xb[i*BATCH]

    float acc[16];
    #pragma unroll 1
    for (int o = 0; o < 16; ++o) {
        const int*   ip = idx_tab + (size_t)(o0 + o) * NACT;
        const float* wp = w_tab   + (size_t)(o0 + o) * NACT;
        // two partial chains: halves the dependent-FMA latency
        float a0 = 0.f, a1 = 0.f;
        #pragma unroll
        for (int k = 0; k < NACT; k += 2) {
            a0 = fmaf(wp[k],   xb[(size_t)ip[k]   * BATCH], a0);
            a1 = fmaf(wp[k+1], xb[(size_t)ip[k+1] * BATCH], a1);
        }
        acc[o] = (a0 + a1) - bias[o0 + o];
    }

    float* op = out + (size_t)b * OUT_DIM + o0;     // 64B-aligned, full line
    #pragma unroll
    for (int q = 0; q < 4; ++q) {
        float4 r; r.x = acc[q*4+0]; r.y = acc[q*4+1];
                  r.z = acc[q*4+2]; r.w = acc[q*4+3];
        *(float4*)(op + q*4) = r;
    }
}

// ---------------------------------------------------------------------------
// Fallback A (ws >= table only): gathers from x directly (uncoalesced, correct).
// ---------------------------------------------------------------------------
__global__ __launch_bounds__(256)
void spmm_noT_kernel(const float* __restrict__ x,
                     const int*   __restrict__ idx_tab,
                     const float* __restrict__ w_tab,
                     const float* __restrict__ bias,
                     float*       __restrict__ out) {
    const int t   = threadIdx.x;
    const int bid = blockIdx.x;           // 4096 blocks
    const int slab = bid >> 8;
    const int ot   = bid & 255;
    const int o0   = ot * 16;
    const int b    = slab * 256 + t;

    float acc[16];
    #pragma unroll 1
    for (int o = 0; o < 16; ++o) {
        const int*   ip = idx_tab + (size_t)(o0 + o) * NACT;
        const float* wp = w_tab   + (size_t)(o0 + o) * NACT;
        float a = 0.f;
        for (int k = 0; k < NACT; ++k)
            a = fmaf(wp[k], x[(size_t)b * IN_DIM + ip[k]], a);
        acc[o] = a - bias[o0 + o];
    }
    float* op = out + (size_t)b * OUT_DIM + o0;
    #pragma unroll
    for (int q = 0; q < 4; ++q) {
        float4 r; r.x = acc[q*4+0]; r.y = acc[q*4+1];
                  r.z = acc[q*4+2]; r.w = acc[q*4+3];
        *(float4*)(op + q*4) = r;
    }
}

// ---------------------------------------------------------------------------
// Fallback B (tiny ws): block per output row; inline compress into LDS.
// ---------------------------------------------------------------------------
__global__ __launch_bounds__(256)
void naive_kernel(const float* __restrict__ x,
                  const float* __restrict__ weight,
                  const float* __restrict__ bias,
                  const int*   __restrict__ mask,
                  float*       __restrict__ out) {
    const int o = blockIdx.x;
    const int t = threadIdx.x;
    __shared__ int   scan[256];
    __shared__ int   sidx[NACT];
    __shared__ float sw[NACT];

    const int* mrow = mask + (size_t)o * IN_DIM;
    const int  base = t * 16;
    int c = 0;
    #pragma unroll
    for (int j = 0; j < 16; ++j) c += (mrow[base + j] != 0);
    scan[t] = c;
    __syncthreads();
    for (int off = 1; off < 256; off <<= 1) {
        int add = (t >= off) ? scan[t - off] : 0;
        __syncthreads();
        scan[t] += add;
        __syncthreads();
    }
    int pos = scan[t] - c;
    for (int j = 0; j < 16; ++j) {
        if (mrow[base + j] != 0) {
            sidx[pos] = base + j;
            sw[pos]   = weight[(size_t)o * IN_DIM + base + j];
            ++pos;
        }
    }
    __syncthreads();
    const float bo = bias[o];
    for (int b = t; b < BATCH; b += 256) {
        float a = 0.f;
        #pragma unroll
        for (int k = 0; k < NACT; ++k)
            a = fmaf(sw[k], x[(size_t)b * IN_DIM + sidx[k]], a);
        out[(size_t)b * OUT_DIM + o] = a - bo;
    }
}

// ---------------------------------------------------------------------------
extern "C" void kernel_launch(void* const* d_in, const int* in_sizes, int n_in,
                              void* d_out, int out_size, void* d_ws, size_t ws_size,
                              hipStream_t stream) {
    const float* x      = (const float*)d_in[0];
    const float* weight = (const float*)d_in[1];
    const float* bias   = (const float*)d_in[2];
    const int*   mask   = (const int*)  d_in[3];
    float* out = (float*)d_out;

    const size_t TAB_BYTES  = (size_t)OUT_DIM * NACT * (sizeof(int) + sizeof(float)); // 1 MB
    const size_t XT_BYTES   = (size_t)IN_DIM * BATCH * sizeof(float);                 // 64 MB
    const size_t NEED_FULL  = TAB_BYTES + XT_BYTES;

    if (ws_size >= NEED_FULL) {
        int*   idx_tab = (int*)d_ws;
        float* w_tab   = (float*)((char*)d_ws + (size_t)OUT_DIM * NACT * sizeof(int));
        float* xT      = (float*)((char*)d_ws + TAB_BYTES);

        compress_kernel<<<OUT_DIM, 256, 0, stream>>>(weight, mask, idx_tab, w_tab);
        dim3 tgrid(BATCH / 64, IN_DIM / 64);
        transpose_kernel<<<tgrid, 256, 0, stream>>>(x, xT);
        spmm_kernel<<<4096, 256, 0, stream>>>(xT, idx_tab, w_tab, bias, out);
    } else if (ws_size >= TAB_BYTES) {
        int*   idx_tab = (int*)d_ws;
        float* w_tab   = (float*)((char*)d_ws + (size_t)OUT_DIM * NACT * sizeof(int));
        compress_kernel<<<OUT_DIM, 256, 0, stream>>>(weight, mask, idx_tab, w_tab);
        spmm_noT_kernel<<<4096, 256, 0, stream>>>(x, idx_tab, w_tab, bias, out);
    } else {
        naive_kernel<<<OUT_DIM, 256, 0, stream>>>(x, weight, bias, mask, out);
    }
}